// Round 10
// baseline (441.774 us; speedup 1.0000x reference)
//
#include <hip/hip_runtime.h>
#include <hip/hip_bf16.h>
#include <hip/hip_cooperative_groups.h>

namespace cg = cooperative_groups;

#define BB 16
#define TT 64
#define SS 256
#define DD 512

typedef __bf16 bf16x8 __attribute__((ext_vector_type(8)));
typedef float f32x4 __attribute__((ext_vector_type(4)));

__device__ __forceinline__ ushort f2b(float x) {
    __hip_bfloat16 h = __float2bfloat16(x);
    return __builtin_bit_cast(ushort, h);
}
__device__ __forceinline__ float b2f(ushort u) {
    unsigned int x = (unsigned int)u << 16;
    return __builtin_bit_cast(float, x);
}
// pack 8 fp32 -> 8 bf16 (RNE, identical to __float2bfloat16 elementwise)
__device__ __forceinline__ uint4 pack8(float4 lo, float4 hi) {
    uint4 r;
    r.x = (unsigned)f2b(lo.x) | ((unsigned)f2b(lo.y) << 16);
    r.y = (unsigned)f2b(lo.z) | ((unsigned)f2b(lo.w) << 16);
    r.z = (unsigned)f2b(hi.x) | ((unsigned)f2b(hi.y) << 16);
    r.w = (unsigned)f2b(hi.z) | ((unsigned)f2b(hi.w) << 16);
    return r;
}

// ---------------- GEMM phase (one 64x64 tile per block), R8-verified -----------
//   [0,128)    mode0: Ewq = exp(2*(src @ W_q^T + b_q))   fp32 (1024x512)
//   [128,256)  mode1: Y   = src @ Wo2^T + b_out          fp32 (1024x512)
//   [256,768)  mode2: EuT[b] = exp(2*(W_c @ mb[b]^T))    bf16, batch b
//   [768,1280) mode3: M2[b]  = mb[b] @ Wo1^T             bf16, batch b
__device__ __forceinline__ void gemm_phase(
    int id, int tid, char* SMEM,
    const float* __restrict__ src, const float* __restrict__ mb,
    const float* __restrict__ wq, const float* __restrict__ wc,
    const float* __restrict__ wo,
    const float* __restrict__ b_q, const float* __restrict__ b_out,
    float* __restrict__ Ewq, float* __restrict__ Y,
    ushort* __restrict__ EuT, ushort* __restrict__ M2) {
    ushort* Asm = (ushort*)SMEM;
    ushort* Bsm = Asm + 64 * 72;
    const float* Ab;
    const float* Bb;
    const float* bias = nullptr;
    void* Cp;
    int ldb, N, m0, n0;
    bool exp2x, obf16, hasb;
    size_t coff = 0;
    if (id < 256) {
        const bool isY = id >= 128;
        const int l = id & 127;
        m0 = (l >> 3) * 64; n0 = (l & 7) * 64;
        Ab = src;
        Bb = isY ? (wo + DD) : wq;
        ldb = isY ? 2 * DD : DD;
        bias = isY ? b_out : b_q;
        hasb = true; exp2x = !isY; obf16 = false; N = DD;
        Cp = isY ? (void*)Y : (void*)Ewq;
    } else if (id < 768) {
        const int l = id - 256;
        const int bz = l >> 5, tl = l & 31;
        m0 = (tl >> 2) * 64; n0 = (tl & 3) * 64;
        Ab = wc;
        Bb = mb + (size_t)bz * SS * DD;
        ldb = DD;
        hasb = false; exp2x = true; obf16 = true; N = SS;
        Cp = (void*)EuT; coff = (size_t)bz * DD * SS;
    } else {
        const int l = id - 768;
        const int bz = l >> 5, tl = l & 31;
        m0 = (tl >> 3) * 64; n0 = (tl & 7) * 64;
        Ab = mb + (size_t)bz * SS * DD;
        Bb = wo;
        ldb = 2 * DD;
        hasb = false; exp2x = false; obf16 = true; N = DD;
        Cp = (void*)M2; coff = (size_t)bz * SS * DD;
    }

    const int lane = tid & 63;
    const int wave = tid >> 6;
    const int wm = wave & 1, wn = wave >> 1;

    const int srow = tid >> 3;
    const int schunk = tid & 7;
    const float* Ag0 = Ab + (size_t)(m0 + srow) * DD + schunk * 8;
    const float* Ag1 = Ag0 + (size_t)32 * DD;
    const float* Bg0 = Bb + (size_t)(n0 + srow) * ldb + schunk * 8;
    const float* Bg1 = Bg0 + (size_t)32 * ldb;
    const int lw = srow * 72 + schunk * 8;

    const int l15 = lane & 15, quad = lane >> 4;
    const int ar = (wm * 32 + l15) * 72 + quad * 8;
    const int br = (wn * 32 + l15) * 72 + quad * 8;

    f32x4 acc00 = {0.f, 0.f, 0.f, 0.f}, acc01 = {0.f, 0.f, 0.f, 0.f};
    f32x4 acc10 = {0.f, 0.f, 0.f, 0.f}, acc11 = {0.f, 0.f, 0.f, 0.f};

    float4 a0l, a0h, a1l, a1h, b0l, b0h, b1l, b1h;
#define LOAD8(ko)                                        \
    a0l = *(const float4*)(Ag0 + (ko));                  \
    a0h = *(const float4*)(Ag0 + (ko) + 4);              \
    a1l = *(const float4*)(Ag1 + (ko));                  \
    a1h = *(const float4*)(Ag1 + (ko) + 4);              \
    b0l = *(const float4*)(Bg0 + (ko));                  \
    b0h = *(const float4*)(Bg0 + (ko) + 4);              \
    b1l = *(const float4*)(Bg1 + (ko));                  \
    b1h = *(const float4*)(Bg1 + (ko) + 4);
#define STORE8()                                         \
    *(uint4*)&Asm[lw] = pack8(a0l, a0h);                 \
    *(uint4*)&Asm[lw + 32 * 72] = pack8(a1l, a1h);       \
    *(uint4*)&Bsm[lw] = pack8(b0l, b0h);                 \
    *(uint4*)&Bsm[lw + 32 * 72] = pack8(b1l, b1h);

    const int P = DD >> 6;
    LOAD8(0)
    for (int p = 0; p < P; ++p) {
        __syncthreads();
        STORE8()
        __syncthreads();
        if (p + 1 < P) { LOAD8((p + 1) << 6) }
        bf16x8 fa0 = *(const bf16x8*)&Asm[ar];
        bf16x8 fa1 = *(const bf16x8*)&Asm[ar + 16 * 72];
        bf16x8 fb0 = *(const bf16x8*)&Bsm[br];
        bf16x8 fb1 = *(const bf16x8*)&Bsm[br + 16 * 72];
        acc00 = __builtin_amdgcn_mfma_f32_16x16x32_bf16(fa0, fb0, acc00, 0, 0, 0);
        acc01 = __builtin_amdgcn_mfma_f32_16x16x32_bf16(fa0, fb1, acc01, 0, 0, 0);
        acc10 = __builtin_amdgcn_mfma_f32_16x16x32_bf16(fa1, fb0, acc10, 0, 0, 0);
        acc11 = __builtin_amdgcn_mfma_f32_16x16x32_bf16(fa1, fb1, acc11, 0, 0, 0);
        fa0 = *(const bf16x8*)&Asm[ar + 32];
        fa1 = *(const bf16x8*)&Asm[ar + 16 * 72 + 32];
        fb0 = *(const bf16x8*)&Bsm[br + 32];
        fb1 = *(const bf16x8*)&Bsm[br + 16 * 72 + 32];
        acc00 = __builtin_amdgcn_mfma_f32_16x16x32_bf16(fa0, fb0, acc00, 0, 0, 0);
        acc01 = __builtin_amdgcn_mfma_f32_16x16x32_bf16(fa0, fb1, acc01, 0, 0, 0);
        acc10 = __builtin_amdgcn_mfma_f32_16x16x32_bf16(fa1, fb0, acc10, 0, 0, 0);
        acc11 = __builtin_amdgcn_mfma_f32_16x16x32_bf16(fa1, fb1, acc11, 0, 0, 0);
    }
#undef LOAD8
#undef STORE8

    const int nA = n0 + wn * 32 + l15;
    float bias0 = 0.f, bias1 = 0.f;
    if (hasb) { bias0 = bias[nA]; bias1 = bias[nA + 16]; }
    float* Cf = (float*)Cp;
    ushort* Cb = (ushort*)Cp;
#pragma unroll
    for (int mt = 0; mt < 2; ++mt) {
        f32x4 accN0 = mt ? acc10 : acc00;
        f32x4 accN1 = mt ? acc11 : acc01;
#pragma unroll
        for (int r = 0; r < 4; ++r) {
            int m = m0 + wm * 32 + mt * 16 + quad * 4 + r;
            float v0 = accN0[r] + bias0;
            float v1 = accN1[r] + bias1;
            if (exp2x) { v0 = __expf(2.0f * v0); v1 = __expf(2.0f * v1); }
            size_t i0 = coff + (size_t)m * N + nA;
            if (obf16) { Cb[i0] = f2b(v0); Cb[i0 + 16] = f2b(v1); }
            else { Cf[i0] = v0; Cf[i0 + 16] = v1; }
        }
    }
}

// ---------------- align phase (R9-verified body, LDS carved from SMEM) ---------
__device__ __forceinline__ void align_phase(
    int b, int tg, int tid, char* SMEM,
    const int* __restrict__ mask, const float* __restrict__ vvec,
    const float* __restrict__ Ewq, const ushort* __restrict__ EuT,
    const ushort* __restrict__ M2, const float* __restrict__ Y,
    float* __restrict__ align_out, float* __restrict__ out0) {
    float4* EL = (float4*)SMEM;                  // 8192
    float* zs0 = (float*)(SMEM + 8192);          // 1024
    float* zs1 = zs0 + 256;                      // 1024
    float4* cmb0 = (float4*)(SMEM + 10240);      // 2048
    float4* cmb1 = cmb0 + 128;                   // 2048
    int* lst0 = (int*)(SMEM + 14336);            // 1024
    int* lst1 = lst0 + 256;                      // 1024
    float* svp = (float*)(SMEM + 16384);         // 16
    int* cnt = (int*)(SMEM + 16400);             // 8

    const int lane = tid & 63;
    const int wave = tid >> 6;
    const int t0 = tg * 2, t1 = t0 + 1;
    const int bt0 = b * TT + t0, bt1 = bt0 + 1;

    if (tid < 2) cnt[tid] = 0;
    const float* E0p = Ewq + (size_t)bt0 * DD;
    const float* E1p = Ewq + (size_t)bt1 * DD;
    float pv = 0.f;
    for (int d = tid; d < DD; d += 256) {
        float vv = vvec[d];
        EL[d] = make_float4(E0p[d], E1p[d], vv, 0.f);
        pv += vv;
    }
#pragma unroll
    for (int off = 32; off > 0; off >>= 1) pv += __shfl_xor(pv, off, 64);
    if (lane == 0) svp[wave] = pv;
    __syncthreads();
    const float sv = svp[0] + svp[1] + svp[2] + svp[3];

    const ushort* U = EuT + (size_t)b * DD * SS + tid;
    float a0 = 0.f, a1 = 0.f;
#pragma unroll 16
    for (int d = 0; d < DD; ++d) {
        float u = b2f(U[(size_t)d * SS]);
        float4 el = EL[d];
        float den0 = __builtin_fmaf(el.x, u, 1.0f);
        float den1 = __builtin_fmaf(el.y, u, 1.0f);
        a0 = __builtin_fmaf(el.z, __builtin_amdgcn_rcpf(den0), a0);
        a1 = __builtin_fmaf(el.z, __builtin_amdgcn_rcpf(den1), a1);
    }
    int mk = mask[b * SS + tid];
    zs0[tid] = mk ? (sv - 2.0f * a0) : -1e9f;
    zs1[tid] = mk ? (sv - 2.0f * a1) : -1e9f;
    __syncthreads();

    if (wave < 2) {
        float* zz = wave ? zs1 : zs0;
        float z0 = zz[lane];
        float z1 = zz[lane + 64];
        float z2 = zz[lane + 128];
        float z3 = zz[lane + 192];
        float mx = fmaxf(fmaxf(z0, z1), fmaxf(z2, z3));
#pragma unroll
        for (int off = 32; off > 0; off >>= 1) mx = fmaxf(mx, __shfl_xor(mx, off, 64));
        z0 -= mx; z1 -= mx; z2 -= mx; z3 -= mx;
        float lo = -1.0f, hi = 0.0f;
        for (int it = 0; it < 24; ++it) {
            float mid = 0.5f * (lo + hi);
            float ssum = fmaxf(z0 - mid, 0.f) + fmaxf(z1 - mid, 0.f) +
                         fmaxf(z2 - mid, 0.f) + fmaxf(z3 - mid, 0.f);
#pragma unroll
            for (int off = 32; off > 0; off >>= 1) ssum += __shfl_xor(ssum, off, 64);
            if (ssum >= 1.0f) lo = mid; else hi = mid;
        }
        float tau = 0.5f * (lo + hi);
        zz[lane] = fmaxf(z0 - tau, 0.f);
        zz[lane + 64] = fmaxf(z1 - tau, 0.f);
        zz[lane + 128] = fmaxf(z2 - tau, 0.f);
        zz[lane + 192] = fmaxf(z3 - tau, 0.f);
    }
    __syncthreads();

    align_out[((size_t)t0 * BB + b) * SS + tid] = zs0[tid];
    align_out[((size_t)t1 * BB + b) * SS + tid] = zs1[tid];

    if (zs0[tid] > 0.f) lst0[atomicAdd(&cnt[0], 1)] = tid;
    if (zs1[tid] > 0.f) lst1[atomicAdd(&cnt[1], 1)] = tid;
    __syncthreads();
    const int n0c = cnt[0], n1c = cnt[1];

    const int ch = tid & 127, sg = tid >> 7;
    const ushort* M2b = M2 + (size_t)b * SS * DD + ch * 4;
    float4 at0 = {0.f, 0.f, 0.f, 0.f}, at1 = {0.f, 0.f, 0.f, 0.f};
#pragma unroll 4
    for (int j = sg; j < n0c; j += 2) {
        int s = lst0[j];
        float p = zs0[s];
        ushort4 m4 = *(const ushort4*)(M2b + (size_t)s * DD);
        at0.x = __builtin_fmaf(p, b2f(m4.x), at0.x);
        at0.y = __builtin_fmaf(p, b2f(m4.y), at0.y);
        at0.z = __builtin_fmaf(p, b2f(m4.z), at0.z);
        at0.w = __builtin_fmaf(p, b2f(m4.w), at0.w);
    }
#pragma unroll 4
    for (int j = sg; j < n1c; j += 2) {
        int s = lst1[j];
        float p = zs1[s];
        ushort4 m4 = *(const ushort4*)(M2b + (size_t)s * DD);
        at1.x = __builtin_fmaf(p, b2f(m4.x), at1.x);
        at1.y = __builtin_fmaf(p, b2f(m4.y), at1.y);
        at1.z = __builtin_fmaf(p, b2f(m4.z), at1.z);
        at1.w = __builtin_fmaf(p, b2f(m4.w), at1.w);
    }
    if (sg == 1) { cmb0[ch] = at0; cmb1[ch] = at1; }
    __syncthreads();
    if (sg == 0) {
        float4 p0 = cmb0[ch], p1 = cmb1[ch];
        const float4* Y0 = (const float4*)(Y + (size_t)bt0 * DD);
        const float4* Y1 = (const float4*)(Y + (size_t)bt1 * DD);
        float4 y0 = Y0[ch], y1 = Y1[ch];
        float4 o0, o1;
        o0.x = at0.x + p0.x + y0.x; o0.y = at0.y + p0.y + y0.y;
        o0.z = at0.z + p0.z + y0.z; o0.w = at0.w + p0.w + y0.w;
        o1.x = at1.x + p1.x + y1.x; o1.y = at1.y + p1.y + y1.y;
        o1.z = at1.z + p1.z + y1.z; o1.w = at1.w + p1.w + y1.w;
        float4* O0 = (float4*)(out0 + ((size_t)t0 * BB + b) * DD);
        float4* O1 = (float4*)(out0 + ((size_t)t1 * BB + b) * DD);
        O0[ch] = o0;
        O1[ch] = o1;
    }
}

// ---------------- cooperative fused kernel (guaranteed co-residency) -----------
__global__ __launch_bounds__(256, 5) void fused_coop(
    const float* __restrict__ src, const float* __restrict__ mb,
    const float* __restrict__ wq, const float* __restrict__ wc,
    const float* __restrict__ wo,
    const float* __restrict__ b_q, const float* __restrict__ b_out,
    const int* __restrict__ mask, const float* __restrict__ vvec,
    float* __restrict__ Ewq, float* __restrict__ Y,
    ushort* __restrict__ EuT, ushort* __restrict__ M2,
    float* __restrict__ align_out, float* __restrict__ out0) {
    __shared__ __align__(16) char SMEM[2 * 64 * 72 * 2];  // 18432 B
    gemm_phase(blockIdx.x, threadIdx.x, SMEM,
               src, mb, wq, wc, wo, b_q, b_out, Ewq, Y, EuT, M2);
    __threadfence();
    cg::this_grid().sync();
    const int id = blockIdx.x;
    if (id >= 256 && id < 768) {
        const int l = id - 256;
        align_phase(l >> 5, l & 31, threadIdx.x, SMEM,
                    mask, vvec, Ewq, EuT, M2, Y, align_out, out0);
    }
}

// ---------------- fallback kernels (R8 two-dispatch path) ----------------------
__global__ __launch_bounds__(256, 5) void mega_gemm(
    const float* __restrict__ src, const float* __restrict__ mb,
    const float* __restrict__ wq, const float* __restrict__ wc,
    const float* __restrict__ wo,
    const float* __restrict__ b_q, const float* __restrict__ b_out,
    float* __restrict__ Ewq, float* __restrict__ Y,
    ushort* __restrict__ EuT, ushort* __restrict__ M2) {
    __shared__ __align__(16) char SMEM[2 * 64 * 72 * 2];
    gemm_phase(blockIdx.x, threadIdx.x, SMEM,
               src, mb, wq, wc, wo, b_q, b_out, Ewq, Y, EuT, M2);
}

__global__ __launch_bounds__(256) void align_k(
    const int* __restrict__ mask, const float* __restrict__ vvec,
    const float* __restrict__ Ewq, const ushort* __restrict__ EuT,
    const ushort* __restrict__ M2, const float* __restrict__ Y,
    float* __restrict__ align_out, float* __restrict__ out0) {
    __shared__ __align__(16) char SMEM[2 * 64 * 72 * 2];
    align_phase(blockIdx.y, blockIdx.x, threadIdx.x, SMEM,
                mask, vvec, Ewq, EuT, M2, Y, align_out, out0);
}

#define S_SRC (BB * TT * DD)
#define S_MB  (BB * SS * DD)

extern "C" void kernel_launch(void* const* d_in, const int* in_sizes, int n_in,
                              void* d_out, int out_size, void* d_ws, size_t ws_size,
                              hipStream_t stream) {
    const float* source = (const float*)d_in[0];       // (B,T,D)
    const float* memory_bank = (const float*)d_in[1];  // (B,S,D)
    const int* memory_mask = (const int*)d_in[2];      // (B,S)
    const float* W_q = (const float*)d_in[3];          // (D,D)
    const float* b_q = (const float*)d_in[4];          // (D,)
    const float* W_c = (const float*)d_in[5];          // (D,D)
    const float* v = (const float*)d_in[6];            // (D,)
    const float* W_out = (const float*)d_in[7];        // (D,2D)
    const float* b_out = (const float*)d_in[8];        // (D,)

    float* out0 = (float*)d_out;                   // attn_h (T,B,D)
    float* out1 = out0 + (size_t)TT * BB * DD;     // align_vectors (T,B,S)

    // workspace (~12 MB)
    float* Ewq = (float*)d_ws;                     // (B*T, D) fp32 exp(2wq)    2 MB
    float* Y = Ewq + S_SRC;                        // (B*T, D) fp32 src@Wo2^T+b 2 MB
    ushort* EuT = (ushort*)(Y + S_SRC);            // (B, D, S) bf16 exp(2uh)   4 MB
    ushort* M2 = EuT + S_MB;                       // (B, S, D) bf16 mb@Wo1^T   4 MB

    void* args[] = {
        (void*)&source, (void*)&memory_bank, (void*)&W_q, (void*)&W_c,
        (void*)&W_out, (void*)&b_q, (void*)&b_out, (void*)&memory_mask,
        (void*)&v, (void*)&Ewq, (void*)&Y, (void*)&EuT, (void*)&M2,
        (void*)&out1, (void*)&out0};
    hipError_t e = hipLaunchCooperativeKernel((const void*)fused_coop,
                                              dim3(1280), dim3(256), args, 0, stream);
    if (e != hipSuccess) {
        (void)hipGetLastError();  // clear, take the proven two-dispatch path
        mega_gemm<<<dim3(1280), dim3(256), 0, stream>>>(
            source, memory_bank, W_q, W_c, W_out, b_q, b_out, Ewq, Y, EuT, M2);
        align_k<<<dim3(32, 16), dim3(256), 0, stream>>>(
            memory_mask, v, Ewq, EuT, M2, Y, out1, out0);
    }
}

// Round 11
// 125.098 us; speedup vs baseline: 3.5314x; 3.5314x over previous
//
#include <hip/hip_runtime.h>
#include <hip/hip_bf16.h>

#define BB 16
#define TT 64
#define SS 256
#define DD 512

typedef __bf16 bf16x8 __attribute__((ext_vector_type(8)));
typedef float f32x4 __attribute__((ext_vector_type(4)));

__device__ __forceinline__ ushort f2b(float x) {
    __hip_bfloat16 h = __float2bfloat16(x);
    return __builtin_bit_cast(ushort, h);
}
__device__ __forceinline__ float b2f(ushort u) {
    unsigned int x = (unsigned int)u << 16;
    return __builtin_bit_cast(float, x);
}

// ---------------- fp32 -> bf16 cast of the 5 GEMM operands, one launch ----------
#define S_SRC (BB * TT * DD)   // 524288
#define S_MB  (BB * SS * DD)   // 2097152
#define S_WQ  (DD * DD)        // 262144
#define S_WC  (DD * DD)        // 262144
#define S_WO  (DD * 2 * DD)    // 524288

__global__ __launch_bounds__(256) void cast_all(
    const float* __restrict__ src, const float* __restrict__ mb,
    const float* __restrict__ wq, const float* __restrict__ wc,
    const float* __restrict__ wo,
    ushort* __restrict__ src_b, ushort* __restrict__ mb_b,
    ushort* __restrict__ wq_b, ushort* __restrict__ wc_b,
    ushort* __restrict__ wo_b) {
    int g = blockIdx.x * 256 + threadIdx.x;  // float4-group index
    const int G0 = S_SRC / 4, G1 = S_MB / 4, G2 = S_WQ / 4, G3 = S_WC / 4;
    const float* in;
    ushort* out;
    int local;
    if (g < G0) { in = src; out = src_b; local = g; }
    else if (g < G0 + G1) { in = mb; out = mb_b; local = g - G0; }
    else if (g < G0 + G1 + G2) { in = wq; out = wq_b; local = g - G0 - G1; }
    else if (g < G0 + G1 + G2 + G3) { in = wc; out = wc_b; local = g - G0 - G1 - G2; }
    else { in = wo; out = wo_b; local = g - G0 - G1 - G2 - G3; }
    float4 x = *(const float4*)(in + (size_t)local * 4);
    ushort4 y = {f2b(x.x), f2b(x.y), f2b(x.z), f2b(x.w)};
    *(ushort4*)(out + (size_t)local * 4) = y;
}

// ---------------- mega-GEMM: all 4 independent GEMMs in one flat grid ----------
// 64x64 tile, BK=64, K=512 (8 phases), lda=512 for every mode.
// Flat block id -> mode:
//   [0,128)    mode0: Ewq = exp(2*(src @ W_q^T + b_q))      fp32 (1024x512)
//   [128,256)  mode1: Y   = src @ Wo2^T + b_out             fp32 (1024x512)
//   [256,768)  mode2: EuT[b] = exp(2*(W_c @ mb[b]^T))       bf16 (512x256), batch 16
//   [768,1280) mode3: M2[b]  = mb[b] @ Wo1^T                bf16 (256x512), batch 16
__global__ __launch_bounds__(256) void mega_gemm(
    const ushort* __restrict__ src_b, const ushort* __restrict__ mb_b,
    const ushort* __restrict__ wqw_b, const ushort* __restrict__ wcw_b,
    const ushort* __restrict__ wo_b,
    const float* __restrict__ b_q, const float* __restrict__ b_out,
    float* __restrict__ Ewq, float* __restrict__ Y,
    ushort* __restrict__ EuT, ushort* __restrict__ M2) {
    __shared__ ushort Asm[64 * 72];
    __shared__ ushort Bsm[64 * 72];
    const int id = blockIdx.x;
    const ushort* Ab;
    const ushort* Bb;
    const float* bias = nullptr;
    void* Cp;
    int ldb, N, m0, n0;
    bool exp2x, obf16, hasb;
    size_t coff = 0;
    if (id < 256) {
        const bool isY = id >= 128;
        const int l = id & 127;
        m0 = (l >> 3) * 64; n0 = (l & 7) * 64;
        Ab = src_b;
        Bb = isY ? (wo_b + DD) : wqw_b;
        ldb = isY ? 2 * DD : DD;
        bias = isY ? b_out : b_q;
        hasb = true; exp2x = !isY; obf16 = false; N = DD;
        Cp = isY ? (void*)Y : (void*)Ewq;
    } else if (id < 768) {
        const int l = id - 256;
        const int bz = l >> 5, tl = l & 31;   // 8 (d) x 4 (s) tiles
        m0 = (tl >> 2) * 64; n0 = (tl & 3) * 64;
        Ab = wcw_b;
        Bb = mb_b + (size_t)bz * SS * DD;
        ldb = DD;
        hasb = false; exp2x = true; obf16 = true; N = SS;
        Cp = (void*)EuT; coff = (size_t)bz * DD * SS;
    } else {
        const int l = id - 768;
        const int bz = l >> 5, tl = l & 31;   // 4 (s) x 8 (d) tiles
        m0 = (tl >> 3) * 64; n0 = (tl & 7) * 64;
        Ab = mb_b + (size_t)bz * SS * DD;
        Bb = wo_b;
        ldb = 2 * DD;
        hasb = false; exp2x = false; obf16 = true; N = DD;
        Cp = (void*)M2; coff = (size_t)bz * SS * DD;
    }

    const int tid = threadIdx.x;
    const int lane = tid & 63;
    const int wave = tid >> 6;
    const int wm = wave & 1, wn = wave >> 1;

    const int srow = tid >> 3;    // 0..31
    const int schunk = tid & 7;   // 8-bf16 chunk within the 64-k slice
    const ushort* Ag0 = Ab + (size_t)(m0 + srow) * DD + schunk * 8;
    const ushort* Ag1 = Ag0 + (size_t)32 * DD;
    const ushort* Bg0 = Bb + (size_t)(n0 + srow) * ldb + schunk * 8;
    const ushort* Bg1 = Bg0 + (size_t)32 * ldb;
    const int lw = srow * 72 + schunk * 8;

    const int l15 = lane & 15, quad = lane >> 4;
    const int ar = (wm * 32 + l15) * 72 + quad * 8;
    const int br = (wn * 32 + l15) * 72 + quad * 8;

    f32x4 acc00 = {0.f, 0.f, 0.f, 0.f}, acc01 = {0.f, 0.f, 0.f, 0.f};
    f32x4 acc10 = {0.f, 0.f, 0.f, 0.f}, acc11 = {0.f, 0.f, 0.f, 0.f};

    uint4 a0 = *(const uint4*)Ag0;
    uint4 a1 = *(const uint4*)Ag1;
    uint4 b0 = *(const uint4*)Bg0;
    uint4 b1 = *(const uint4*)Bg1;
    const int P = DD >> 6;  // 8 phases
    for (int p = 0; p < P; ++p) {
        __syncthreads();  // prior phase's ds_reads complete
        *(uint4*)&Asm[lw] = a0;
        *(uint4*)&Asm[lw + 32 * 72] = a1;
        *(uint4*)&Bsm[lw] = b0;
        *(uint4*)&Bsm[lw + 32 * 72] = b1;
        __syncthreads();
        if (p + 1 < P) {  // prefetch next slice, overlaps compute below
            int ko = (p + 1) << 6;
            a0 = *(const uint4*)(Ag0 + ko);
            a1 = *(const uint4*)(Ag1 + ko);
            b0 = *(const uint4*)(Bg0 + ko);
            b1 = *(const uint4*)(Bg1 + ko);
        }
        bf16x8 fa0 = *(const bf16x8*)&Asm[ar];
        bf16x8 fa1 = *(const bf16x8*)&Asm[ar + 16 * 72];
        bf16x8 fb0 = *(const bf16x8*)&Bsm[br];
        bf16x8 fb1 = *(const bf16x8*)&Bsm[br + 16 * 72];
        acc00 = __builtin_amdgcn_mfma_f32_16x16x32_bf16(fa0, fb0, acc00, 0, 0, 0);
        acc01 = __builtin_amdgcn_mfma_f32_16x16x32_bf16(fa0, fb1, acc01, 0, 0, 0);
        acc10 = __builtin_amdgcn_mfma_f32_16x16x32_bf16(fa1, fb0, acc10, 0, 0, 0);
        acc11 = __builtin_amdgcn_mfma_f32_16x16x32_bf16(fa1, fb1, acc11, 0, 0, 0);
        fa0 = *(const bf16x8*)&Asm[ar + 32];
        fa1 = *(const bf16x8*)&Asm[ar + 16 * 72 + 32];
        fb0 = *(const bf16x8*)&Bsm[br + 32];
        fb1 = *(const bf16x8*)&Bsm[br + 16 * 72 + 32];
        acc00 = __builtin_amdgcn_mfma_f32_16x16x32_bf16(fa0, fb0, acc00, 0, 0, 0);
        acc01 = __builtin_amdgcn_mfma_f32_16x16x32_bf16(fa0, fb1, acc01, 0, 0, 0);
        acc10 = __builtin_amdgcn_mfma_f32_16x16x32_bf16(fa1, fb0, acc10, 0, 0, 0);
        acc11 = __builtin_amdgcn_mfma_f32_16x16x32_bf16(fa1, fb1, acc11, 0, 0, 0);
    }
    // epilogue: C/D layout col=l15, row=quad*4+reg
    const int nA = n0 + wn * 32 + l15;
    float bias0 = 0.f, bias1 = 0.f;
    if (hasb) { bias0 = bias[nA]; bias1 = bias[nA + 16]; }
    float* Cf = (float*)Cp;
    ushort* Cb = (ushort*)Cp;
#pragma unroll
    for (int mt = 0; mt < 2; ++mt) {
        f32x4 accN0 = mt ? acc10 : acc00;
        f32x4 accN1 = mt ? acc11 : acc01;
#pragma unroll
        for (int r = 0; r < 4; ++r) {
            int m = m0 + wm * 32 + mt * 16 + quad * 4 + r;
            float v0 = accN0[r] + bias0;
            float v1 = accN1[r] + bias1;
            if (exp2x) { v0 = __expf(2.0f * v0); v1 = __expf(2.0f * v1); }
            size_t i0 = coff + (size_t)m * N + nA;
            if (obf16) { Cb[i0] = f2b(v0); Cb[i0 + 16] = f2b(v1); }
            else { Cf[i0] = v0; Cf[i0 + 16] = v1; }
        }
    }
}

// ---------------- fused align + sparsemax + output ------------------------------
// Block = (2 t-rows, b). scores via sum_d v_d tanh(w+u) = sumv - 2*sum v_d/(E*U+1);
// E/v preloaded to LDS (broadcast ds_read_b128/iter), U bf16 (B,D,S) coalesced.
// Output attn = p @ M2[b] + Y, using compacted sparsemax support lists.
__global__ __launch_bounds__(256) void align5(const float* __restrict__ Ewq,
                                              const ushort* __restrict__ EuT,
                                              const int* __restrict__ mask,
                                              const float* __restrict__ v,
                                              const ushort* __restrict__ M2,
                                              const float* __restrict__ Y,
                                              float* __restrict__ align_out,
                                              float* __restrict__ out0) {
    const int tg = blockIdx.x, b = blockIdx.y;
    const int t0 = tg * 2, t1 = t0 + 1;
    const int bt0 = b * TT + t0, bt1 = bt0 + 1;
    const int tid = threadIdx.x;
    const int lane = tid & 63;
    const int wave = tid >> 6;
    __shared__ float4 EL[DD];       // {E0, E1, v, -} 8 KB
    __shared__ float zs0[SS], zs1[SS];
    __shared__ float svp[4];
    __shared__ float4 cmb[2][128];  // output partial combine
    __shared__ int lst0[SS], lst1[SS];
    __shared__ int cnt[2];

    if (tid < 2) cnt[tid] = 0;
    // preload EL + sum(v)
    const float* E0p = Ewq + (size_t)bt0 * DD;
    const float* E1p = Ewq + (size_t)bt1 * DD;
    float pv = 0.f;
    for (int d = tid; d < DD; d += 256) {
        float vv = v[d];
        EL[d] = make_float4(E0p[d], E1p[d], vv, 0.f);
        pv += vv;
    }
#pragma unroll
    for (int off = 32; off > 0; off >>= 1) pv += __shfl_xor(pv, off, 64);
    if (lane == 0) svp[wave] = pv;
    __syncthreads();
    const float sv = svp[0] + svp[1] + svp[2] + svp[3];

    // scores: thread owns s = tid
    const ushort* U = EuT + (size_t)b * DD * SS + tid;
    float a0 = 0.f, a1 = 0.f;
#pragma unroll 16
    for (int d = 0; d < DD; ++d) {
        float u = b2f(U[(size_t)d * SS]);
        float4 el = EL[d];
        float den0 = __builtin_fmaf(el.x, u, 1.0f);
        float den1 = __builtin_fmaf(el.y, u, 1.0f);
        a0 = __builtin_fmaf(el.z, __builtin_amdgcn_rcpf(den0), a0);
        a1 = __builtin_fmaf(el.z, __builtin_amdgcn_rcpf(den1), a1);
    }
    int mk = mask[b * SS + tid];
    zs0[tid] = mk ? (sv - 2.0f * a0) : -1e9f;
    zs1[tid] = mk ? (sv - 2.0f * a1) : -1e9f;
    __syncthreads();

    // sparsemax: wave 0 -> zs0, wave 1 -> zs1 (shuffle-only)
    if (wave < 2) {
        float* zz = wave ? zs1 : zs0;
        float z0 = zz[lane];
        float z1 = zz[lane + 64];
        float z2 = zz[lane + 128];
        float z3 = zz[lane + 192];
        float mx = fmaxf(fmaxf(z0, z1), fmaxf(z2, z3));
#pragma unroll
        for (int off = 32; off > 0; off >>= 1) mx = fmaxf(mx, __shfl_xor(mx, off, 64));
        z0 -= mx; z1 -= mx; z2 -= mx; z3 -= mx;
        float lo = -1.0f, hi = 0.0f;
        for (int it = 0; it < 24; ++it) {
            float mid = 0.5f * (lo + hi);
            float ssum = fmaxf(z0 - mid, 0.f) + fmaxf(z1 - mid, 0.f) +
                         fmaxf(z2 - mid, 0.f) + fmaxf(z3 - mid, 0.f);
#pragma unroll
            for (int off = 32; off > 0; off >>= 1) ssum += __shfl_xor(ssum, off, 64);
            if (ssum >= 1.0f) lo = mid; else hi = mid;
        }
        float tau = 0.5f * (lo + hi);
        zz[lane] = fmaxf(z0 - tau, 0.f);
        zz[lane + 64] = fmaxf(z1 - tau, 0.f);
        zz[lane + 128] = fmaxf(z2 - tau, 0.f);
        zz[lane + 192] = fmaxf(z3 - tau, 0.f);
    }
    __syncthreads();

    align_out[((size_t)t0 * BB + b) * SS + tid] = zs0[tid];
    align_out[((size_t)t1 * BB + b) * SS + tid] = zs1[tid];

    // compact support lists (order-free; sum commutes)
    if (zs0[tid] > 0.f) lst0[atomicAdd(&cnt[0], 1)] = tid;
    if (zs1[tid] > 0.f) lst1[atomicAdd(&cnt[1], 1)] = tid;
    __syncthreads();
    const int n0c = cnt[0], n1c = cnt[1];

    // out rows: thread ch = tid&127 owns d = ch*4..+3 for BOTH t; sg splits list
    const int ch = tid & 127, sg = tid >> 7;
    const ushort* M2b = M2 + (size_t)b * SS * DD + ch * 4;
    float4 at0 = {0.f, 0.f, 0.f, 0.f}, at1 = {0.f, 0.f, 0.f, 0.f};
#pragma unroll 4
    for (int j = sg; j < n0c; j += 2) {
        int s = lst0[j];
        float p = zs0[s];
        ushort4 m4 = *(const ushort4*)(M2b + (size_t)s * DD);
        at0.x = __builtin_fmaf(p, b2f(m4.x), at0.x);
        at0.y = __builtin_fmaf(p, b2f(m4.y), at0.y);
        at0.z = __builtin_fmaf(p, b2f(m4.z), at0.z);
        at0.w = __builtin_fmaf(p, b2f(m4.w), at0.w);
    }
#pragma unroll 4
    for (int j = sg; j < n1c; j += 2) {
        int s = lst1[j];
        float p = zs1[s];
        ushort4 m4 = *(const ushort4*)(M2b + (size_t)s * DD);
        at1.x = __builtin_fmaf(p, b2f(m4.x), at1.x);
        at1.y = __builtin_fmaf(p, b2f(m4.y), at1.y);
        at1.z = __builtin_fmaf(p, b2f(m4.z), at1.z);
        at1.w = __builtin_fmaf(p, b2f(m4.w), at1.w);
    }
    if (sg == 1) { cmb[0][ch] = at0; cmb[1][ch] = at1; }
    __syncthreads();
    if (sg == 0) {
        float4 p0 = cmb[0][ch], p1 = cmb[1][ch];
        const float4* Y0 = (const float4*)(Y + (size_t)bt0 * DD);
        const float4* Y1 = (const float4*)(Y + (size_t)bt1 * DD);
        float4 y0 = Y0[ch], y1 = Y1[ch];
        float4 o0, o1;
        o0.x = at0.x + p0.x + y0.x; o0.y = at0.y + p0.y + y0.y;
        o0.z = at0.z + p0.z + y0.z; o0.w = at0.w + p0.w + y0.w;
        o1.x = at1.x + p1.x + y1.x; o1.y = at1.y + p1.y + y1.y;
        o1.z = at1.z + p1.z + y1.z; o1.w = at1.w + p1.w + y1.w;
        float4* O0 = (float4*)(out0 + ((size_t)t0 * BB + b) * DD);
        float4* O1 = (float4*)(out0 + ((size_t)t1 * BB + b) * DD);
        O0[ch] = o0;
        O1[ch] = o1;
    }
}

extern "C" void kernel_launch(void* const* d_in, const int* in_sizes, int n_in,
                              void* d_out, int out_size, void* d_ws, size_t ws_size,
                              hipStream_t stream) {
    const float* source = (const float*)d_in[0];       // (B,T,D)
    const float* memory_bank = (const float*)d_in[1];  // (B,S,D)
    const int* memory_mask = (const int*)d_in[2];      // (B,S)
    const float* W_q = (const float*)d_in[3];          // (D,D)
    const float* b_q = (const float*)d_in[4];          // (D,)
    const float* W_c = (const float*)d_in[5];          // (D,D)
    const float* v = (const float*)d_in[6];            // (D,)
    const float* W_out = (const float*)d_in[7];        // (D,2D)
    const float* b_out = (const float*)d_in[8];        // (D,)

    float* out0 = (float*)d_out;                   // attn_h (T,B,D)
    float* out1 = out0 + (size_t)TT * BB * DD;     // align_vectors (T,B,S)

    // workspace (~19.3 MB)
    float* Ewq = (float*)d_ws;                     // (B*T, D) fp32 exp(2wq)  2 MB
    float* Y = Ewq + S_SRC;                        // (B*T, D) fp32 src@Wo2^T+b 2 MB
    ushort* EuT = (ushort*)(Y + S_SRC);            // (B, D, S) bf16 exp(2uh) 4 MB
    ushort* M2 = EuT + S_MB;                       // (B, S, D) bf16 mb@Wo1^T 4 MB
    ushort* src_b = M2 + S_MB;                     // 1 MB
    ushort* mb_b = src_b + S_SRC;                  // 4 MB
    ushort* wqw_b = mb_b + S_MB;                   // 0.5 MB
    ushort* wcw_b = wqw_b + S_WQ;                  // 0.5 MB
    ushort* wo_b = wcw_b + S_WC;                   // 1 MB

    dim3 blk(256);
    // 1. cast bf16 operands
    int ngroups = (S_SRC + S_MB + S_WQ + S_WC + S_WO) / 4;
    cast_all<<<dim3(ngroups / 256), blk, 0, stream>>>(
        source, memory_bank, W_q, W_c, W_out, src_b, mb_b, wqw_b, wcw_b, wo_b);
    // 2. all four GEMMs, one dispatch (1280 blocks ~ 5/CU)
    mega_gemm<<<dim3(1280), blk, 0, stream>>>(
        src_b, mb_b, wqw_b, wcw_b, wo_b, b_q, b_out, Ewq, Y, EuT, M2);
    // 3. fused align + sparsemax + output
    align5<<<dim3(TT / 2, BB), blk, 0, stream>>>(
        Ewq, EuT, memory_mask, v, M2, Y, out1, out0);
}